// Round 4
// baseline (26.562 us; speedup 1.0000x reference)
//
#include <hip/hip_runtime.h>
#include <hip/hip_bf16.h>

// Problem: B=32, T=1024, D=512, x float32 (B,T,D) viewed flat as per-batch
// row-major M[D][T].  Row 0 = padding, rows 1..D-1 = signal.
//   norm[t]      = sum_{d=1..D-1} |M[d][t]|
//   one_minus[t] = 1 / (1 + exp(M[0][t] - norm[t]))
//   out[0][t]    = M[0][t] * (1 + |padding_amount|)
//   out[d][t]    = M[d][t] * one_minus[t]                 (d >= 1)
//
// R4: software-pipelined grid-stride.  Each block owns 4 column-tiles and
// ping-pongs two register buffers: while tile k is reduced/stored, tile
// k+1's loads are in flight.  Barriers use raw s_barrier + lgkmcnt(0) ONLY
// (hipcc's __syncthreads drains vmcnt(0), which would kill the overlap).
// Result: continuous mixed read+write traffic instead of GPU-wide
// read-phase / drain / write-phase alternation.

#define BB 32
#define TT 1024
#define DD 512

constexpr int TB    = 32;             // columns per tile
constexpr int WAVES = 4;              // 256 threads per block
constexpr int R     = 16;             // float4 rows per thread
constexpr int NTILE = 4;              // tiles per block (pipeline depth)

// LDS-visibility barrier that does NOT drain vmcnt: prefetched global loads
// stay in flight across it.  "memory" clobbers pin LDS op ordering.
__device__ __forceinline__ void lds_barrier() {
    asm volatile("s_waitcnt lgkmcnt(0)" ::: "memory");
    __builtin_amdgcn_s_barrier();
    asm volatile("" ::: "memory");
}

__global__ __launch_bounds__(256) void padding_bottleneck_kernel(
    const float* __restrict__ x,
    const float* __restrict__ padding_amount,
    float* __restrict__ out)
{
    const int blk  = blockIdx.x;           // 0..255  (= 1 block per CU)
    const int b    = blk >> 3;             // batch
    const int tgrp = blk & 7;              // tile group: tiles 4*tgrp..+3
    const int lane = threadIdx.x & 63;
    const int wav  = threadIdx.x >> 6;     // 0..3
    const int cg   = lane & 7;             // column group (4 cols)
    const int rg   = lane >> 3;            // row group 0..7
    const int c0   = cg * 4;
    const int r0   = wav * (DD / WAVES) + rg * R;

    const size_t base = (size_t)b * DD * TT + (size_t)r0 * TT
                      + (size_t)(tgrp * (NTILE * TB)) + c0;
    const float* src = x + base;
    float*       dst = out + base;

    __shared__ float psum[WAVES][TB];
    __shared__ float padv[TB];

    const bool  has_pad = (wav == 0 && rg == 0);  // this thread's j==0 is row d=0
    const float scale   = 1.f + fabsf(padding_amount[0]);

    float4 va[R], vb[R];

    auto load_tile = [&](float4 (&v)[R], int t) {
#pragma unroll
        for (int j = 0; j < R; ++j)
            v[j] = *reinterpret_cast<const float4*>(src + (size_t)j * TT + t * TB);
    };

    auto process_tile = [&](float4 (&v)[R], int t) {
        // per-column |.| partials (waits only on this buffer's loads;
        // newer prefetch loads remain outstanding)
        float s0 = 0.f, s1 = 0.f, s2 = 0.f, s3 = 0.f;
#pragma unroll
        for (int j = 0; j < R; ++j) {
            s0 += fabsf(v[j].x); s1 += fabsf(v[j].y);
            s2 += fabsf(v[j].z); s3 += fabsf(v[j].w);
        }
        if (has_pad) {
            s0 -= fabsf(v[0].x); s1 -= fabsf(v[0].y);
            s2 -= fabsf(v[0].z); s3 -= fabsf(v[0].w);
            *reinterpret_cast<float4*>(&padv[c0]) = v[0];
        }
        // fold 8 row-groups within the wave
        s0 += __shfl_xor(s0, 8);  s1 += __shfl_xor(s1, 8);
        s2 += __shfl_xor(s2, 8);  s3 += __shfl_xor(s3, 8);
        s0 += __shfl_xor(s0, 16); s1 += __shfl_xor(s1, 16);
        s2 += __shfl_xor(s2, 16); s3 += __shfl_xor(s3, 16);
        s0 += __shfl_xor(s0, 32); s1 += __shfl_xor(s1, 32);
        s2 += __shfl_xor(s2, 32); s3 += __shfl_xor(s3, 32);
        if (rg == 0)
            *reinterpret_cast<float4*>(&psum[wav][c0]) = make_float4(s0, s1, s2, s3);
        lds_barrier();

        float n0 = 0.f, n1 = 0.f, n2 = 0.f, n3 = 0.f;
#pragma unroll
        for (int s = 0; s < WAVES; ++s) {
            float4 p = *reinterpret_cast<const float4*>(&psum[s][c0]);
            n0 += p.x; n1 += p.y; n2 += p.z; n3 += p.w;
        }
        const float4 pv = *reinterpret_cast<const float4*>(&padv[c0]);
        const float om0 = 1.f / (1.f + __expf(pv.x - n0));
        const float om1 = 1.f / (1.f + __expf(pv.y - n1));
        const float om2 = 1.f / (1.f + __expf(pv.z - n2));
        const float om3 = 1.f / (1.f + __expf(pv.w - n3));

#pragma unroll
        for (int j = 0; j < R; ++j) {
            float4 o;
            if (has_pad && j == 0) {
                o.x = v[0].x * scale; o.y = v[0].y * scale;
                o.z = v[0].z * scale; o.w = v[0].w * scale;
            } else {
                o.x = v[j].x * om0; o.y = v[j].y * om1;
                o.z = v[j].z * om2; o.w = v[j].w * om3;
            }
            *reinterpret_cast<float4*>(dst + (size_t)j * TT + t * TB) = o;
        }
        lds_barrier();   // protect psum/padv reuse next tile
    };

    // ---- pipelined schedule: loads of tile k+1 overlap store of tile k
    load_tile(va, 0);
    load_tile(vb, 1);  process_tile(va, 0);
    load_tile(va, 2);  process_tile(vb, 1);
    load_tile(vb, 3);  process_tile(va, 2);
                       process_tile(vb, 3);
}

extern "C" void kernel_launch(void* const* d_in, const int* in_sizes, int n_in,
                              void* d_out, int out_size, void* d_ws, size_t ws_size,
                              hipStream_t stream)
{
    const float* x  = (const float*)d_in[0];
    const float* pa = (const float*)d_in[1];
    float* out      = (float*)d_out;

    // one block per (batch, 4-tile group): 32 * 8 = 256 blocks = 1 per CU
    dim3 grid(BB * (TT / (NTILE * TB)));
    dim3 block(WAVES * 64);
    padding_bottleneck_kernel<<<grid, block, 0, stream>>>(x, pa, out);
}

// Round 5
// 24.525 us; speedup vs baseline: 1.0830x; 1.0830x over previous
//
#include <hip/hip_runtime.h>
#include <hip/hip_bf16.h>

// Problem: B=32, T=1024, D=512, x float32 (B,T,D) viewed flat as per-batch
// row-major M[D][T].  Row 0 = padding, rows 1..D-1 = signal.
//   norm[t]      = sum_{d=1..D-1} |M[d][t]|
//   one_minus[t] = 1 / (1 + exp(M[0][t] - norm[t]))
//   out[0][t]    = M[0][t] * (1 + |padding_amount|)
//   out[d][t]    = M[d][t] * one_minus[t]                 (d >= 1)
//
// R5: de-phase-lock probe.  Many small autonomous blocks instead of few
// phase-locked ones.  Block = 128 threads (2 waves) owning a 32-col x
// 512-row tile; 4 blocks/CU finish & get replaced at staggered times, so
// the GPU carries mixed read+write traffic continuously instead of
// alternating read-epoch / barrier / write-epoch.
//   lane: cg = lane&7 -> 4 adjacent cols (float4, 8x16B = one 128B line),
//         rg = lane>>3 -> 8 row-groups of 32 rows.  wave w owns rows
//         [256w, 256w+256).  Per-thread cache: 32 x float4 = 128 VGPRs.
//   Norm: shfl_xor(8,16,32) folds the 8 row-groups; tiny 2-wave LDS
//   exchange (psum4[2][8]) + one __syncthreads (vmcnt already drained by
//   the sum chain, so the implicit drain is free).

#define BB 32
#define TT 1024
#define DD 512

constexpr int TBC = 32;               // columns per block tile
constexpr int R   = 32;               // float4 rows per thread

__global__ __launch_bounds__(128, 3) void padding_bottleneck_kernel(
    const float* __restrict__ x,
    const float* __restrict__ padding_amount,
    float* __restrict__ out)
{
    const int blk  = blockIdx.x;            // 0..1023
    const int b    = blk >> 5;              // batch
    const int ct   = blk & 31;              // 32-col tile within batch
    const int lane = threadIdx.x & 63;
    const int wv   = threadIdx.x >> 6;      // 0..1
    const int cg   = lane & 7;              // column group (4 cols, 16 B)
    const int rg   = lane >> 3;             // row group 0..7 (32 rows each)
    const int c0   = ct * TBC + cg * 4;
    const int r0   = wv * 256 + rg * R;

    const size_t base = (size_t)b * DD * TT + (size_t)r0 * TT + c0;
    const float* src = x + base;
    float*       dst = out + base;

    // ---- pass 1: load 32 float4 into registers, per-column |.| partials
    float4 v[R];
    float s0 = 0.f, s1 = 0.f, s2 = 0.f, s3 = 0.f;
#pragma unroll
    for (int j = 0; j < R; ++j) {
        v[j] = *reinterpret_cast<const float4*>(src + (size_t)j * TT);
        s0 += fabsf(v[j].x); s1 += fabsf(v[j].y);
        s2 += fabsf(v[j].z); s3 += fabsf(v[j].w);
    }

    __shared__ float4 psum4[2][8];
    __shared__ float4 padv4[8];

    const bool has_pad = (wv == 0 && rg == 0);   // j==0 is global row d=0
    if (has_pad) {
        s0 -= fabsf(v[0].x); s1 -= fabsf(v[0].y);
        s2 -= fabsf(v[0].z); s3 -= fabsf(v[0].w);
        padv4[cg] = v[0];
    }

    // ---- fold the 8 row-groups of this wave (lane bits 3..5)
    s0 += __shfl_xor(s0, 8);  s1 += __shfl_xor(s1, 8);
    s2 += __shfl_xor(s2, 8);  s3 += __shfl_xor(s3, 8);
    s0 += __shfl_xor(s0, 16); s1 += __shfl_xor(s1, 16);
    s2 += __shfl_xor(s2, 16); s3 += __shfl_xor(s3, 16);
    s0 += __shfl_xor(s0, 32); s1 += __shfl_xor(s1, 32);
    s2 += __shfl_xor(s2, 32); s3 += __shfl_xor(s3, 32);

    if (rg == 0) psum4[wv][cg] = make_float4(s0, s1, s2, s3);
    __syncthreads();

    // ---- per-column weight (2-wave combine)
    const float4 pa0 = psum4[0][cg];
    const float4 pa1 = psum4[1][cg];
    const float4 pv  = padv4[cg];
    const float om0 = 1.f / (1.f + __expf(pv.x - (pa0.x + pa1.x)));
    const float om1 = 1.f / (1.f + __expf(pv.y - (pa0.y + pa1.y)));
    const float om2 = 1.f / (1.f + __expf(pv.z - (pa0.z + pa1.z)));
    const float om3 = 1.f / (1.f + __expf(pv.w - (pa0.w + pa1.w)));
    const float scale = 1.f + fabsf(padding_amount[0]);

    // ---- pass 2: scale cached registers, store float4
#pragma unroll
    for (int j = 0; j < R; ++j) {
        float4 o;
        if (has_pad && j == 0) {
            o.x = v[0].x * scale; o.y = v[0].y * scale;
            o.z = v[0].z * scale; o.w = v[0].w * scale;
        } else {
            o.x = v[j].x * om0; o.y = v[j].y * om1;
            o.z = v[j].z * om2; o.w = v[j].w * om3;
        }
        *reinterpret_cast<float4*>(dst + (size_t)j * TT) = o;
    }
}

extern "C" void kernel_launch(void* const* d_in, const int* in_sizes, int n_in,
                              void* d_out, int out_size, void* d_ws, size_t ws_size,
                              hipStream_t stream)
{
    const float* x  = (const float*)d_in[0];
    const float* pa = (const float*)d_in[1];
    float* out      = (float*)d_out;

    // one block per (batch, 32-col tile): 32 * 32 = 1024 blocks, 128 thr each
    dim3 grid(BB * (TT / TBC));
    dim3 block(128);
    padding_bottleneck_kernel<<<grid, block, 0, stream>>>(x, pa, out);
}